// Round 1
// 3007.399 us; speedup vs baseline: 1.8279x; 1.8279x over previous
//
#include <hip/hip_runtime.h>

typedef unsigned short u16;
typedef unsigned int u32;
typedef _Float16 h4 __attribute__((ext_vector_type(4)));
typedef _Float16 h8 __attribute__((ext_vector_type(8)));
typedef float f32x4 __attribute__((ext_vector_type(4)));

#define MFMA16(a, b, c) __builtin_amdgcn_mfma_f32_16x16x32_f16((a), (b), (c), 0, 0, 0)

__device__ __forceinline__ float wsum(float v) {
  #pragma unroll
  for (int o = 32; o > 0; o >>= 1) v += __shfl_down(v, o);
  return __shfl(v, 0);
}
__device__ __forceinline__ float wmax(float v) {
  #pragma unroll
  for (int o = 32; o > 0; o >>= 1) v = fmaxf(v, __shfl_down(v, o));
  return __shfl(v, 0);
}

// ---------- K0: transpose f32 [R][Cc] -> [Cc][R] (fc1 weights for k_mlp) ----------
__global__ void k_trf(const float* __restrict__ in, float* __restrict__ out, int R, int Cc) {
  int e = blockIdx.x * 256 + threadIdx.x;
  if (e < R * Cc) {
    int r = e / Cc, c = e - r * Cc;
    out[(size_t)c * R + r] = in[e];
  }
}

// ---------- prep: qkv_w f32 [256k][768c] -> fp16 [row = h*96 + mat*32 + cc][256 k] ----------
__global__ void k_prep_qkv(const float* __restrict__ w, _Float16* __restrict__ o) {
  const int e = blockIdx.x * 256 + threadIdx.x;   // 768*256
  const int r = e >> 8, k = e & 255;
  const int h = r / 96, rem = r - h * 96;
  const int mat = rem >> 5, cc = rem & 31;
  o[e] = (_Float16)w[k * 768 + mat * 256 + h * 32 + cc];
}

// ---------- prep: proj_w f32 [256 in][256 out] -> fp16 [out][in] (k-contiguous) ----------
__global__ void k_prep_pw(const float* __restrict__ w, _Float16* __restrict__ o) {
  const int e = blockIdx.x * 256 + threadIdx.x;   // 256*256
  const int oc = e >> 8, ic = e & 255;
  o[e] = (_Float16)w[ic * 256 + oc];
}

// ---------- K1: LN1 + shift + window + qkv + attn + softmax + PV + proj + residual (MFMA) ----
// one block per window (2048 blocks), 256 threads = 4 waves.
// LDS map (bytes):
//   ZN  [0,25088)   : LN out fp16, rows 0..48 x 256ch, row-major, XOR ((row&7)<<4) swizzle.
//                     Fragment reads for pad rows 49..63 read harmlessly into Q/K (garbage,
//                     row-isolated in MFMA, never stored).
//   Q   [25088,30208): per-head q fp16 [64 tok][40 slots] (80B rows, 32 used). Reused as O_h.
//   K   [30208,35328): per-head k fp16, same layout.
//   V   [35328,39424): per-head v fp16, token-chunked: (tok,ch) -> (tok>>3)*512 + ch*16 + (tok&7)*2
//   ATT [39424,51968): scores f32 [49][64], (n,m) -> (n*256+m*4) ^ ((n&3)<<6)
//   P   [51968,60160): softmax fp16 [64][64], (n,m) -> (n*128+m*2) ^ ((n&7)<<4)
#define ZN_OFF  0
#define Q_OFF   25088
#define K_OFF   30208
#define V_OFF   35328
#define ATT_OFF 39424
#define P_OFF   51968
#define SMEM_SZ 60160

__global__ __launch_bounds__(256, 2) void k_attn(
    const float* __restrict__ x, const _Float16* __restrict__ wsq,
    const _Float16* __restrict__ pwh, const float* __restrict__ qkvb,
    const float* __restrict__ g1, const float* __restrict__ b1,
    const float* __restrict__ temp, const int* __restrict__ rpi,
    const float* __restrict__ rtab, const float* __restrict__ amask,
    const float* __restrict__ pb, float* __restrict__ io) {
  __shared__ __align__(16) char smem[SMEM_SZ];
  const int tid = threadIdx.x;
  const int lane = tid & 63, w = tid >> 6;
  const int lr = lane & 15, lk = lane >> 4;
  const int win = blockIdx.x;
  const int bb = win >> 6, wimg = win & 63;
  const int hb = wimg >> 3, wb = wimg & 7;
  const float scale = expf(temp[0]);
  const int swz = (lr & 7) << 4;   // row-swizzle for ZN/P fragment reads (row&7 == lr&7)

  // --- LN1 over C=256 at shifted source coords (roll(-3)) -> ZN fp16 ---
  {
    const float4 gz = ((const float4*)g1)[lane];
    const float4 bz = ((const float4*)b1)[lane];
    for (int n = w; n < 49; n += 4) {
      int i = n / 7, j = n - 7 * i;
      int rs = hb * 7 + i + 3; if (rs >= 56) rs -= 56;
      int cs = wb * 7 + j + 3; if (cs >= 56) cs -= 56;
      const float4 p = ((const float4*)(x + ((size_t)bb * 3136 + rs * 56 + cs) * 256))[lane];
      float mean = wsum(p.x + p.y + p.z + p.w) * (1.f / 256.f);
      float d0 = p.x - mean, d1 = p.y - mean, d2 = p.z - mean, d3 = p.w - mean;
      float var = wsum(d0 * d0 + d1 * d1 + d2 * d2 + d3 * d3) * (1.f / 256.f);
      float rstd = rsqrtf(var + 1e-6f);
      h4 z;
      z[0] = (_Float16)(d0 * rstd * gz.x + bz.x);
      z[1] = (_Float16)(d1 * rstd * gz.y + bz.y);
      z[2] = (_Float16)(d2 * rstd * gz.z + bz.z);
      z[3] = (_Float16)(d3 * rstd * gz.w + bz.w);
      *(h4*)(smem + ((n * 512 + lane * 8) ^ ((n & 7) << 4))) = z;
    }
  }
  __syncthreads();

  // proj accumulator: wave w owns out-cols [64w, 64w+64); pacc[tn][nt] = 16x16 D tile
  f32x4 pacc[4][4];
  #pragma unroll
  for (int a = 0; a < 4; ++a)
    #pragma unroll
    for (int c = 0; c < 4; ++c) {
      f32x4 z = {0.f, 0.f, 0.f, 0.f};
      pacc[a][c] = z;
    }

  // qkv tile split: 24 tiles (6 strips x 4 tn) -> wave w gets tile ids 6w..6w+5
  const int s0 = (6 * w) >> 2, s1 = (6 * w + 5) >> 2;
  const int rb0 = (((2 * w + 0) & 3) * 16 + lr) * 512;
  const int rb1 = (((2 * w + 1) & 3) * 16 + lr) * 512;
  const int rb2 = (((2 * w + 2) & 3) * 16 + lr) * 512;
  const int rb3 = (((2 * w + 3) & 3) * 16 + lr) * 512;

  for (int h = 0; h < 8; ++h) {
    // ---- stage B: qkv head slice, (64x256)@(256x96) via MFMA ----
    f32x4 zz4 = {0.f, 0.f, 0.f, 0.f};
    f32x4 ac0 = zz4, ac1 = zz4, ac2 = zz4, ac3 = zz4, ac4 = zz4, ac5 = zz4;
    {
      const _Float16* wr0 = wsq + ((size_t)(h * 96 + s0 * 16 + lr) * 256 + lk * 8);
      const _Float16* wr1 = wsq + ((size_t)(h * 96 + s1 * 16 + lr) * 256 + lk * 8);
      #pragma unroll
      for (int ks = 0; ks < 8; ++ks) {
        const int ko = ks * 64 + lk * 16;
        h8 a0 = *(const h8*)(smem + ((rb0 + ko) ^ swz));
        h8 a1 = *(const h8*)(smem + ((rb1 + ko) ^ swz));
        h8 a2 = *(const h8*)(smem + ((rb2 + ko) ^ swz));
        h8 a3 = *(const h8*)(smem + ((rb3 + ko) ^ swz));
        h8 b0 = *(const h8*)(wr0 + ks * 32);
        h8 b1 = *(const h8*)(wr1 + ks * 32);
        ac0 = MFMA16(a0, b0, ac0);
        ac1 = MFMA16(a1, b0, ac1);
        if (w & 1) { ac2 = MFMA16(a2, b1, ac2); ac3 = MFMA16(a3, b1, ac3); }
        else       { ac2 = MFMA16(a2, b0, ac2); ac3 = MFMA16(a3, b0, ac3); }
        ac4 = MFMA16(a0, b1, ac4);
        ac5 = MFMA16(a1, b1, ac5);
      }
    }
    // D -> LDS (q scaled by exp(temp); pad tokens >=49 written as 0 — NaN-safe for PV)
    {
      auto dwr = [&](int idx, f32x4 ac) {
        const int t6 = 6 * w + idx;
        const int strip = t6 >> 2, tn = t6 & 3;
        const int mat = strip >> 1;
        const int cc = (strip & 1) * 16 + lr;
        const float bias = qkvb[mat * 256 + h * 32 + cc];
        const int tok0 = tn * 16 + lk * 4;
        if (mat == 2) {
          h4 pk;
          #pragma unroll
          for (int r = 0; r < 4; ++r) {
            float v = (tok0 + r < 49) ? (ac[r] + bias) : 0.f;
            pk[r] = (_Float16)v;
          }
          *(h4*)(smem + V_OFF + (tok0 >> 3) * 512 + cc * 16 + (tok0 & 7) * 2) = pk;
        } else {
          const float mult = (mat == 0) ? scale : 1.f;
          char* base = smem + (mat == 0 ? Q_OFF : K_OFF);
          #pragma unroll
          for (int r = 0; r < 4; ++r) {
            int tok = tok0 + r;
            float v = (tok < 49) ? (ac[r] + bias) * mult : 0.f;
            *(_Float16*)(base + tok * 80 + cc * 2) = (_Float16)v;
          }
        }
      };
      dwr(0, ac0); dwr(1, ac1); dwr(2, ac2); dwr(3, ac3); dwr(4, ac4); dwr(5, ac5);
    }
    __syncthreads();

    // ---- stage C: scores S = QK^T (wave w -> row tile tn=w), + diag/bias/mask, dump ----
    {
      h8 aq  = *(const h8*)(smem + Q_OFF + (w * 16 + lr) * 80 + lk * 16);
      h8 bk0 = *(const h8*)(smem + K_OFF + (lr) * 80 + lk * 16);
      h8 bk1 = *(const h8*)(smem + K_OFF + (16 + lr) * 80 + lk * 16);
      h8 bk2 = *(const h8*)(smem + K_OFF + (32 + lr) * 80 + lk * 16);
      h8 bk3 = *(const h8*)(smem + K_OFF + (48 + lr) * 80 + lk * 16);
      f32x4 sc0 = MFMA16(aq, bk0, zz4);
      f32x4 sc1 = MFMA16(aq, bk1, zz4);
      f32x4 sc2 = MFMA16(aq, bk2, zz4);
      f32x4 sc3 = MFMA16(aq, bk3, zz4);
      auto dump = [&](f32x4 sv4, int tm) {
        #pragma unroll
        for (int r = 0; r < 4; ++r) {
          const int n = w * 16 + lk * 4 + r;
          if (n < 49) {
            const int m = tm * 16 + lr;
            float sv;
            if (m >= 49) sv = -1e38f;
            else {
              sv = sv4[r];
              if (m == n) sv = -1e30f;             // LSA diag BEFORE bias/mask (per ref)
              const int e = n * 49 + m;
              sv += rtab[(size_t)rpi[e] * 8 + h] + amask[(size_t)wimg * 2401 + e];
            }
            *(float*)(smem + ATT_OFF + ((n * 256 + m * 4) ^ ((n & 3) << 6))) = sv;
          }
        }
      };
      dump(sc0, 0); dump(sc1, 1); dump(sc2, 2); dump(sc3, 3);
    }
    __syncthreads();

    // ---- stage D: softmax per row; P fp16 (cols >=49 -> exactly 0) ----
    for (int n = w; n < 49; n += 4) {
      const float s = *(const float*)(smem + ATT_OFF + ((n * 256 + lane * 4) ^ ((n & 3) << 6)));
      const float mx = wmax(s);
      const float e = expf(s - mx);
      const float sm = wsum(e);
      *(_Float16*)(smem + P_OFF + ((n * 128 + lane * 2) ^ ((n & 7) << 4))) = (_Float16)(e / sm);
    }
    __syncthreads();

    // ---- stage E: O_h = P @ V (wave w -> row tile tn=w), stage into Q region (q is dead) ----
    {
      f32x4 o0 = zz4, o1 = zz4;
      const int prow = w * 16 + lr;
      #pragma unroll
      for (int ks = 0; ks < 2; ++ks) {
        h8 ap  = *(const h8*)(smem + P_OFF + ((prow * 128 + ks * 64 + lk * 16) ^ swz));
        h8 bv0 = *(const h8*)(smem + V_OFF + (ks * 4 + lk) * 512 + lr * 16);
        h8 bv1 = *(const h8*)(smem + V_OFF + (ks * 4 + lk) * 512 + (16 + lr) * 16);
        o0 = MFMA16(ap, bv0, o0);
        o1 = MFMA16(ap, bv1, o1);
      }
      #pragma unroll
      for (int r = 0; r < 4; ++r) {
        const int tok = w * 16 + lk * 4 + r;
        *(_Float16*)(smem + Q_OFF + tok * 80 + lr * 2) = (_Float16)o0[r];
        *(_Float16*)(smem + Q_OFF + tok * 80 + (16 + lr) * 2) = (_Float16)o1[r];
      }
    }
    __syncthreads();

    // ---- stage F: proj partial, pacc += O_h @ pw[h*32.., :] (wave w -> cols 64w..64w+63) ----
    {
      h8 pa0 = *(const h8*)(smem + Q_OFF + (lr) * 80 + lk * 16);
      h8 pa1 = *(const h8*)(smem + Q_OFF + (16 + lr) * 80 + lk * 16);
      h8 pa2 = *(const h8*)(smem + Q_OFF + (32 + lr) * 80 + lk * 16);
      h8 pa3 = *(const h8*)(smem + Q_OFF + (48 + lr) * 80 + lk * 16);
      const _Float16* pwr = pwh + (size_t)(w * 64 + lr) * 256 + h * 32 + lk * 8;
      #pragma unroll
      for (int nt = 0; nt < 4; ++nt) {
        h8 bw = *(const h8*)(pwr + (size_t)nt * 16 * 256);
        pacc[0][nt] = MFMA16(pa0, bw, pacc[0][nt]);
        pacc[1][nt] = MFMA16(pa1, bw, pacc[1][nt]);
        pacc[2][nt] = MFMA16(pa2, bw, pacc[2][nt]);
        pacc[3][nt] = MFMA16(pa3, bw, pacc[3][nt]);
      }
    }
    __syncthreads();   // protect Q/K/V/ATT/P before next head
  }

  // ---- epilogue: reverse shift + residual -> io (f32) ----
  {
    const float pb0 = pb[w * 64 + lr];
    const float pb1 = pb[w * 64 + 16 + lr];
    const float pb2 = pb[w * 64 + 32 + lr];
    const float pb3 = pb[w * 64 + 48 + lr];
    #pragma unroll
    for (int tn = 0; tn < 4; ++tn) {
      #pragma unroll
      for (int r = 0; r < 4; ++r) {
        const int tok = tn * 16 + lk * 4 + r;
        if (tok < 49) {
          const int i = tok / 7, j = tok - 7 * i;
          int rs = hb * 7 + i + 3; if (rs >= 56) rs -= 56;
          int cs = wb * 7 + j + 3; if (cs >= 56) cs -= 56;
          const size_t ro = ((size_t)bb * 3136 + rs * 56 + cs) * 256 + w * 64 + lr;
          io[ro]      = x[ro]      + pacc[tn][0][r] + pb0;
          io[ro + 16] = x[ro + 16] + pacc[tn][1][r] + pb1;
          io[ro + 32] = x[ro + 32] + pacc[tn][2][r] + pb2;
          io[ro + 48] = x[ro + 48] + pacc[tn][3][r] + pb3;
        }
      }
    }
  }
}

// ---------- K2: LN2 + fc1 + GELU + fc2 + residual (unchanged, f32) ----------
__global__ __launch_bounds__(256) void k_mlp(
    float* __restrict__ io, const float* __restrict__ g2, const float* __restrict__ b2,
    const float* __restrict__ fc1T, const float* __restrict__ fb1,
    const float* __restrict__ w2p, const float* __restrict__ fb2) {
  __shared__ __align__(16) float ln_s[32][256];
  __shared__ __align__(16) float t1T[64][36];
  const int tid = threadIdx.x;
  const int lane = tid & 63, wv = tid >> 6;
  const size_t t0 = (size_t)blockIdx.x * 32;

  {
    const float4 gz = ((const float4*)g2)[lane];
    const float4 bz = ((const float4*)b2)[lane];
    for (int n = wv; n < 32; n += 4) {
      const float4 p = ((const float4*)(io + (t0 + n) * 256))[lane];
      float mean = wsum(p.x + p.y + p.z + p.w) * (1.f / 256.f);
      float d0 = p.x - mean, d1 = p.y - mean, d2 = p.z - mean, d3 = p.w - mean;
      float var = wsum(d0 * d0 + d1 * d1 + d2 * d2 + d3 * d3) * (1.f / 256.f);
      float rstd = rsqrtf(var + 1e-6f);
      ((float4*)&ln_s[n][0])[lane] =
          make_float4(d0 * rstd * gz.x + bz.x, d1 * rstd * gz.y + bz.y,
                      d2 * rstd * gz.z + bz.z, d3 * rstd * gz.w + bz.w);
    }
  }
  __syncthreads();

  float acc32[32];
  #pragma unroll
  for (int n = 0; n < 32; ++n) acc32[n] = 0.f;
  const int col = lane;

  for (int ch = 0; ch < 16; ++ch) {
    float acc8[8];
    #pragma unroll
    for (int r = 0; r < 8; ++r) acc8[r] = 0.f;
    const float4* wrow = (const float4*)(fc1T + (size_t)(ch * 64 + col) * 256);
    for (int c4 = 0; c4 < 64; ++c4) {
      const float4 w4 = wrow[c4];
      #pragma unroll
      for (int r = 0; r < 8; ++r) {
        const float4 l = ((const float4*)&ln_s[wv + (r << 2)][0])[c4];
        acc8[r] += l.x * w4.x + l.y * w4.y + l.z * w4.z + l.w * w4.w;
      }
    }
    {
      const float bb = fb1[ch * 64 + col];
      #pragma unroll
      for (int r = 0; r < 8; ++r) {
        float a = acc8[r] + bb;
        t1T[col][wv + (r << 2)] = 0.5f * a * (1.f + erff(a * 0.70710678118654752f));
      }
    }
    __syncthreads();
    for (int m = 0; m < 64; ++m) {
      const float w = w2p[(size_t)(ch * 64 + m) * 256 + tid];
      const float4* tr = (const float4*)&t1T[m][0];
      #pragma unroll
      for (int n4 = 0; n4 < 8; ++n4) {
        const float4 t = tr[n4];
        acc32[n4 * 4 + 0] += t.x * w; acc32[n4 * 4 + 1] += t.y * w;
        acc32[n4 * 4 + 2] += t.z * w; acc32[n4 * 4 + 3] += t.w * w;
      }
    }
    __syncthreads();
  }

  const float b2v = fb2[tid];
  #pragma unroll
  for (int n = 0; n < 32; ++n) {
    size_t idx = (t0 + n) * 256 + tid;
    io[idx] = io[idx] + acc32[n] + b2v;
  }
}

extern "C" void kernel_launch(void* const* d_in, const int* in_sizes, int n_in,
                              void* d_out, int out_size, void* d_ws, size_t ws_size,
                              hipStream_t stream) {
  const float* x     = (const float*)d_in[0];
  const float* amask = (const float*)d_in[1];
  const float* g1    = (const float*)d_in[2];
  const float* b1    = (const float*)d_in[3];
  const float* qkvw  = (const float*)d_in[4];
  const float* qkvb  = (const float*)d_in[5];
  const float* temp  = (const float*)d_in[6];
  const float* rtab  = (const float*)d_in[7];
  const float* pw    = (const float*)d_in[8];
  const float* pb    = (const float*)d_in[9];
  const float* g2    = (const float*)d_in[10];
  const float* b2    = (const float*)d_in[11];
  const float* w1    = (const float*)d_in[12];
  const float* fb1   = (const float*)d_in[13];
  const float* w2    = (const float*)d_in[14];
  const float* fb2   = (const float*)d_in[15];
  const int* rpi     = (const int*)d_in[16];
  // d_in[17], d_in[18] = H, W (fixed 56)

  char* ws = (char*)d_ws;
  _Float16* wsq = (_Float16*)ws;              // 393,216 B (768x256 fp16, k-contiguous)
  _Float16* pwh = (_Float16*)(ws + 393216);   // 131,072 B (256x256 fp16, k-contiguous)
  float* fc1T   = (float*)(ws + 524288);      // 1,048,576 B (1024x256 f32)
  float* io     = (float*)d_out;

  k_prep_qkv<<<768, 256, 0, stream>>>(qkvw, wsq);
  k_prep_pw<<<256, 256, 0, stream>>>(pw, pwh);
  k_trf<<<1024, 256, 0, stream>>>(w1, fc1T, 256, 1024);
  k_attn<<<2048, 256, 0, stream>>>(x, wsq, pwh, qkvb, g1, b1, temp, rpi, rtab,
                                   amask, pb, io);
  k_mlp<<<3136, 256, 0, stream>>>(io, g2, b2, fc1T, fb1, w2, fb2);
}

// Round 4
// 1194.073 us; speedup vs baseline: 4.6037x; 2.5186x over previous
//
#include <hip/hip_runtime.h>

typedef unsigned short u16;
typedef unsigned int u32;
typedef _Float16 h4 __attribute__((ext_vector_type(4)));
typedef _Float16 h8 __attribute__((ext_vector_type(8)));
typedef float f32x4 __attribute__((ext_vector_type(4)));

#define MFMA16(a, b, c) __builtin_amdgcn_mfma_f32_16x16x32_f16((a), (b), (c), 0, 0, 0)

__device__ __forceinline__ float wsum(float v) {
  #pragma unroll
  for (int o = 32; o > 0; o >>= 1) v += __shfl_down(v, o);
  return __shfl(v, 0);
}
__device__ __forceinline__ float wmax(float v) {
  #pragma unroll
  for (int o = 32; o > 0; o >>= 1) v = fmaxf(v, __shfl_down(v, o));
  return __shfl(v, 0);
}

// ---------- prep: qkv_w f32 [256k][768c] -> fp16 [row = h*96 + mat*32 + cc][256 k] ----------
__global__ void k_prep_qkv(const float* __restrict__ w, _Float16* __restrict__ o) {
  const int e = blockIdx.x * 256 + threadIdx.x;   // 768*256
  const int r = e >> 8, k = e & 255;
  const int h = r / 96, rem = r - h * 96;
  const int mat = rem >> 5, cc = rem & 31;
  o[e] = (_Float16)w[k * 768 + mat * 256 + h * 32 + cc];
}

// ---------- prep: proj_w f32 [256 in][256 out] -> fp16 [out][in] (k-contiguous) ----------
__global__ void k_prep_pw(const float* __restrict__ w, _Float16* __restrict__ o) {
  const int e = blockIdx.x * 256 + threadIdx.x;   // 256*256
  const int oc = e >> 8, ic = e & 255;
  o[e] = (_Float16)w[ic * 256 + oc];
}

// ---------- prep: fc1_w f32 [256k][1024c] -> fp16 [col][256 k] ----------
__global__ void k_prep_w1(const float* __restrict__ w, _Float16* __restrict__ o) {
  const int e = blockIdx.x * 256 + threadIdx.x;   // 1024*256
  const int col = e >> 8, k = e & 255;
  o[e] = (_Float16)w[k * 1024 + col];
}

// ---------- prep: fc2_w f32 [1024k][256c] -> fp16 [col][1024 k] ----------
__global__ void k_prep_w2(const float* __restrict__ w, _Float16* __restrict__ o) {
  const int e = blockIdx.x * 256 + threadIdx.x;   // 256*1024
  const int oc = e >> 10, k = e & 1023;
  o[e] = (_Float16)w[k * 256 + oc];
}

// ---------- K1: LN1 + shift + window + qkv + attn + softmax + PV + proj + residual (MFMA) ----
// one block per window (2048 blocks), 256 threads = 4 waves.
#define ZN_OFF  0
#define Q_OFF   25088
#define K_OFF   30208
#define V_OFF   35328
#define ATT_OFF 39424
#define P_OFF   51968
#define SMEM_SZ 60160

__global__ __launch_bounds__(256, 2) void k_attn(
    const float* __restrict__ x, const _Float16* __restrict__ wsq,
    const _Float16* __restrict__ pwh, const float* __restrict__ qkvb,
    const float* __restrict__ g1, const float* __restrict__ b1,
    const float* __restrict__ temp, const int* __restrict__ rpi,
    const float* __restrict__ rtab, const float* __restrict__ amask,
    const float* __restrict__ pb, float* __restrict__ io) {
  __shared__ __align__(16) char smem[SMEM_SZ];
  const int tid = threadIdx.x;
  const int lane = tid & 63, w = tid >> 6;
  const int lr = lane & 15, lk = lane >> 4;
  const int win = blockIdx.x;
  const int bb = win >> 6, wimg = win & 63;
  const int hb = wimg >> 3, wb = wimg & 7;
  const float scale = expf(temp[0]);
  const int swz = (lr & 7) << 4;

  // --- LN1 over C=256 at shifted source coords (roll(-3)) -> ZN fp16 ---
  {
    const float4 gz = ((const float4*)g1)[lane];
    const float4 bz = ((const float4*)b1)[lane];
    for (int n = w; n < 49; n += 4) {
      int i = n / 7, j = n - 7 * i;
      int rs = hb * 7 + i + 3; if (rs >= 56) rs -= 56;
      int cs = wb * 7 + j + 3; if (cs >= 56) cs -= 56;
      const float4 p = ((const float4*)(x + ((size_t)bb * 3136 + rs * 56 + cs) * 256))[lane];
      float mean = wsum(p.x + p.y + p.z + p.w) * (1.f / 256.f);
      float d0 = p.x - mean, d1 = p.y - mean, d2 = p.z - mean, d3 = p.w - mean;
      float var = wsum(d0 * d0 + d1 * d1 + d2 * d2 + d3 * d3) * (1.f / 256.f);
      float rstd = rsqrtf(var + 1e-6f);
      h4 z;
      z[0] = (_Float16)(d0 * rstd * gz.x + bz.x);
      z[1] = (_Float16)(d1 * rstd * gz.y + bz.y);
      z[2] = (_Float16)(d2 * rstd * gz.z + bz.z);
      z[3] = (_Float16)(d3 * rstd * gz.w + bz.w);
      *(h4*)(smem + ((n * 512 + lane * 8) ^ ((n & 7) << 4))) = z;
    }
  }
  __syncthreads();

  f32x4 pacc[4][4];
  #pragma unroll
  for (int a = 0; a < 4; ++a)
    #pragma unroll
    for (int c = 0; c < 4; ++c) {
      f32x4 z = {0.f, 0.f, 0.f, 0.f};
      pacc[a][c] = z;
    }

  const int s0 = (6 * w) >> 2, s1 = (6 * w + 5) >> 2;
  const int rb0 = (((2 * w + 0) & 3) * 16 + lr) * 512;
  const int rb1 = (((2 * w + 1) & 3) * 16 + lr) * 512;
  const int rb2 = (((2 * w + 2) & 3) * 16 + lr) * 512;
  const int rb3 = (((2 * w + 3) & 3) * 16 + lr) * 512;

  for (int h = 0; h < 8; ++h) {
    // ---- stage B: qkv head slice, (64x256)@(256x96) via MFMA ----
    f32x4 zz4 = {0.f, 0.f, 0.f, 0.f};
    f32x4 ac0 = zz4, ac1 = zz4, ac2 = zz4, ac3 = zz4, ac4 = zz4, ac5 = zz4;
    {
      const _Float16* wr0 = wsq + ((size_t)(h * 96 + s0 * 16 + lr) * 256 + lk * 8);
      const _Float16* wr1 = wsq + ((size_t)(h * 96 + s1 * 16 + lr) * 256 + lk * 8);
      #pragma unroll
      for (int ks = 0; ks < 8; ++ks) {
        const int ko = ks * 64 + lk * 16;
        h8 a0 = *(const h8*)(smem + ((rb0 + ko) ^ swz));
        h8 a1 = *(const h8*)(smem + ((rb1 + ko) ^ swz));
        h8 a2 = *(const h8*)(smem + ((rb2 + ko) ^ swz));
        h8 a3 = *(const h8*)(smem + ((rb3 + ko) ^ swz));
        h8 b0 = *(const h8*)(wr0 + ks * 32);
        h8 b1 = *(const h8*)(wr1 + ks * 32);
        ac0 = MFMA16(a0, b0, ac0);
        ac1 = MFMA16(a1, b0, ac1);
        if (w & 1) { ac2 = MFMA16(a2, b1, ac2); ac3 = MFMA16(a3, b1, ac3); }
        else       { ac2 = MFMA16(a2, b0, ac2); ac3 = MFMA16(a3, b0, ac3); }
        ac4 = MFMA16(a0, b1, ac4);
        ac5 = MFMA16(a1, b1, ac5);
      }
    }
    {
      auto dwr = [&](int idx, f32x4 ac) {
        const int t6 = 6 * w + idx;
        const int strip = t6 >> 2, tn = t6 & 3;
        const int mat = strip >> 1;
        const int cc = (strip & 1) * 16 + lr;
        const float bias = qkvb[mat * 256 + h * 32 + cc];
        const int tok0 = tn * 16 + lk * 4;
        if (mat == 2) {
          h4 pk;
          #pragma unroll
          for (int r = 0; r < 4; ++r) {
            float v = (tok0 + r < 49) ? (ac[r] + bias) : 0.f;
            pk[r] = (_Float16)v;
          }
          *(h4*)(smem + V_OFF + (tok0 >> 3) * 512 + cc * 16 + (tok0 & 7) * 2) = pk;
        } else {
          const float mult = (mat == 0) ? scale : 1.f;
          char* base = smem + (mat == 0 ? Q_OFF : K_OFF);
          #pragma unroll
          for (int r = 0; r < 4; ++r) {
            int tok = tok0 + r;
            float v = (tok < 49) ? (ac[r] + bias) * mult : 0.f;
            *(_Float16*)(base + tok * 80 + cc * 2) = (_Float16)v;
          }
        }
      };
      dwr(0, ac0); dwr(1, ac1); dwr(2, ac2); dwr(3, ac3); dwr(4, ac4); dwr(5, ac5);
    }
    __syncthreads();

    // ---- stage C: scores S = QK^T + diag/bias/mask ----
    {
      h8 aq  = *(const h8*)(smem + Q_OFF + (w * 16 + lr) * 80 + lk * 16);
      h8 bk0 = *(const h8*)(smem + K_OFF + (lr) * 80 + lk * 16);
      h8 bk1 = *(const h8*)(smem + K_OFF + (16 + lr) * 80 + lk * 16);
      h8 bk2 = *(const h8*)(smem + K_OFF + (32 + lr) * 80 + lk * 16);
      h8 bk3 = *(const h8*)(smem + K_OFF + (48 + lr) * 80 + lk * 16);
      f32x4 sc0 = MFMA16(aq, bk0, zz4);
      f32x4 sc1 = MFMA16(aq, bk1, zz4);
      f32x4 sc2 = MFMA16(aq, bk2, zz4);
      f32x4 sc3 = MFMA16(aq, bk3, zz4);
      auto dump = [&](f32x4 sv4, int tm) {
        #pragma unroll
        for (int r = 0; r < 4; ++r) {
          const int n = w * 16 + lk * 4 + r;
          if (n < 49) {
            const int m = tm * 16 + lr;
            float sv;
            if (m >= 49) sv = -1e38f;
            else {
              sv = sv4[r];
              if (m == n) sv = -1e30f;
              const int e = n * 49 + m;
              sv += rtab[(size_t)rpi[e] * 8 + h] + amask[(size_t)wimg * 2401 + e];
            }
            *(float*)(smem + ATT_OFF + ((n * 256 + m * 4) ^ ((n & 3) << 6))) = sv;
          }
        }
      };
      dump(sc0, 0); dump(sc1, 1); dump(sc2, 2); dump(sc3, 3);
    }
    __syncthreads();

    // ---- stage D: softmax per row ----
    for (int n = w; n < 49; n += 4) {
      const float s = *(const float*)(smem + ATT_OFF + ((n * 256 + lane * 4) ^ ((n & 3) << 6)));
      const float mx = wmax(s);
      const float e = expf(s - mx);
      const float sm = wsum(e);
      *(_Float16*)(smem + P_OFF + ((n * 128 + lane * 2) ^ ((n & 7) << 4))) = (_Float16)(e / sm);
    }
    __syncthreads();

    // ---- stage E: O_h = P @ V -> stage into Q region ----
    {
      f32x4 o0 = zz4, o1 = zz4;
      const int prow = w * 16 + lr;
      #pragma unroll
      for (int ks = 0; ks < 2; ++ks) {
        h8 ap  = *(const h8*)(smem + P_OFF + ((prow * 128 + ks * 64 + lk * 16) ^ swz));
        h8 bv0 = *(const h8*)(smem + V_OFF + (ks * 4 + lk) * 512 + lr * 16);
        h8 bv1 = *(const h8*)(smem + V_OFF + (ks * 4 + lk) * 512 + (16 + lr) * 16);
        o0 = MFMA16(ap, bv0, o0);
        o1 = MFMA16(ap, bv1, o1);
      }
      #pragma unroll
      for (int r = 0; r < 4; ++r) {
        const int tok = w * 16 + lk * 4 + r;
        *(_Float16*)(smem + Q_OFF + tok * 80 + lr * 2) = (_Float16)o0[r];
        *(_Float16*)(smem + Q_OFF + tok * 80 + (16 + lr) * 2) = (_Float16)o1[r];
      }
    }
    __syncthreads();

    // ---- stage F: proj partial ----
    {
      h8 pa0 = *(const h8*)(smem + Q_OFF + (lr) * 80 + lk * 16);
      h8 pa1 = *(const h8*)(smem + Q_OFF + (16 + lr) * 80 + lk * 16);
      h8 pa2 = *(const h8*)(smem + Q_OFF + (32 + lr) * 80 + lk * 16);
      h8 pa3 = *(const h8*)(smem + Q_OFF + (48 + lr) * 80 + lk * 16);
      const _Float16* pwr = pwh + (size_t)(w * 64 + lr) * 256 + h * 32 + lk * 8;
      #pragma unroll
      for (int nt = 0; nt < 4; ++nt) {
        h8 bw = *(const h8*)(pwr + (size_t)nt * 16 * 256);
        pacc[0][nt] = MFMA16(pa0, bw, pacc[0][nt]);
        pacc[1][nt] = MFMA16(pa1, bw, pacc[1][nt]);
        pacc[2][nt] = MFMA16(pa2, bw, pacc[2][nt]);
        pacc[3][nt] = MFMA16(pa3, bw, pacc[3][nt]);
      }
    }
    __syncthreads();
  }

  // ---- epilogue: reverse shift + residual -> io (f32) ----
  {
    const float pb0 = pb[w * 64 + lr];
    const float pb1 = pb[w * 64 + 16 + lr];
    const float pb2 = pb[w * 64 + 32 + lr];
    const float pb3 = pb[w * 64 + 48 + lr];
    #pragma unroll
    for (int tn = 0; tn < 4; ++tn) {
      #pragma unroll
      for (int r = 0; r < 4; ++r) {
        const int tok = tn * 16 + lk * 4 + r;
        if (tok < 49) {
          const int i = tok / 7, j = tok - 7 * i;
          int rs = hb * 7 + i + 3; if (rs >= 56) rs -= 56;
          int cs = wb * 7 + j + 3; if (cs >= 56) cs -= 56;
          const size_t ro = ((size_t)bb * 3136 + rs * 56 + cs) * 256 + w * 64 + lr;
          io[ro]      = x[ro]      + pacc[tn][0][r] + pb0;
          io[ro + 16] = x[ro + 16] + pacc[tn][1][r] + pb1;
          io[ro + 32] = x[ro + 32] + pacc[tn][2][r] + pb2;
          io[ro + 48] = x[ro + 48] + pacc[tn][3][r] + pb3;
        }
      }
    }
  }
}

// ---------- K2: LN2 + fc1 + GELU + fc2 + residual via MFMA ----------
// 64 tokens/block (1568 blocks), 256 threads = 4 waves.
// LDS: ZN fp16 [64][256] swizzled @0 (32 KB); H fp16 [64][256] swizzled @32768 (32 KB).
// H col for wave w = w*64 + nt*16 + lr  ->  byte = tok*512 + w*128 + nt*32 + lr*2 (then row XOR).
#define MH_OFF 32768

__global__ __launch_bounds__(256, 2) void k_mlp2(
    float* __restrict__ io, const float* __restrict__ g2, const float* __restrict__ b2,
    const _Float16* __restrict__ w1h, const float* __restrict__ fb1,
    const _Float16* __restrict__ w2h, const float* __restrict__ fb2) {
  __shared__ __align__(16) char smem[65536];
  const int tid = threadIdx.x;
  const int lane = tid & 63, w = tid >> 6;
  const int lr = lane & 15, lk = lane >> 4;
  const size_t t0 = (size_t)blockIdx.x * 64;
  const int swz = (lr & 7) << 4;

  // --- LN2 -> ZN fp16 ---
  {
    const float4 gz = ((const float4*)g2)[lane];
    const float4 bz = ((const float4*)b2)[lane];
    for (int n = w; n < 64; n += 4) {
      const float4 p = ((const float4*)(io + (t0 + n) * 256))[lane];
      float mean = wsum(p.x + p.y + p.z + p.w) * (1.f / 256.f);
      float d0 = p.x - mean, d1 = p.y - mean, d2 = p.z - mean, d3 = p.w - mean;
      float var = wsum(d0 * d0 + d1 * d1 + d2 * d2 + d3 * d3) * (1.f / 256.f);
      float rstd = rsqrtf(var + 1e-6f);
      h4 z;
      z[0] = (_Float16)(d0 * rstd * gz.x + bz.x);
      z[1] = (_Float16)(d1 * rstd * gz.y + bz.y);
      z[2] = (_Float16)(d2 * rstd * gz.z + bz.z);
      z[3] = (_Float16)(d3 * rstd * gz.w + bz.w);
      *(h4*)(smem + ((n * 512 + lane * 8) ^ ((n & 7) << 4))) = z;
    }
  }
  __syncthreads();

  f32x4 zz = {0.f, 0.f, 0.f, 0.f};
  f32x4 oacc[4][4];   // [tn][nt], out col = w*64 + nt*16 + lr, tok = tn*16 + lk*4 + r
  #pragma unroll
  for (int a = 0; a < 4; ++a)
    #pragma unroll
    for (int c = 0; c < 4; ++c) oacc[a][c] = zz;

  for (int ch = 0; ch < 4; ++ch) {
    // ---- fc1 chunk: F = ZN @ W1[:, ch*256 + w*64 .. +64) ----
    f32x4 facc[4][4];
    #pragma unroll
    for (int a = 0; a < 4; ++a)
      #pragma unroll
      for (int c = 0; c < 4; ++c) facc[a][c] = zz;
    {
      const _Float16* w1p = w1h + (size_t)(ch * 256 + w * 64 + lr) * 256 + lk * 8;
      #pragma unroll
      for (int ks = 0; ks < 8; ++ks) {
        const int ko = ks * 64 + lk * 16;
        h8 a0 = *(const h8*)(smem + (((0 * 16 + lr) * 512 + ko) ^ swz));
        h8 a1 = *(const h8*)(smem + (((1 * 16 + lr) * 512 + ko) ^ swz));
        h8 a2 = *(const h8*)(smem + (((2 * 16 + lr) * 512 + ko) ^ swz));
        h8 a3 = *(const h8*)(smem + (((3 * 16 + lr) * 512 + ko) ^ swz));
        h8 b0 = *(const h8*)(w1p + 0 * 16 * 256 + ks * 32);
        h8 b1 = *(const h8*)(w1p + 1 * 16 * 256 + ks * 32);
        h8 b2_ = *(const h8*)(w1p + 2 * 16 * 256 + ks * 32);
        h8 b3 = *(const h8*)(w1p + 3 * 16 * 256 + ks * 32);
        facc[0][0] = MFMA16(a0, b0, facc[0][0]);
        facc[1][0] = MFMA16(a1, b0, facc[1][0]);
        facc[2][0] = MFMA16(a2, b0, facc[2][0]);
        facc[3][0] = MFMA16(a3, b0, facc[3][0]);
        facc[0][1] = MFMA16(a0, b1, facc[0][1]);
        facc[1][1] = MFMA16(a1, b1, facc[1][1]);
        facc[2][1] = MFMA16(a2, b1, facc[2][1]);
        facc[3][1] = MFMA16(a3, b1, facc[3][1]);
        facc[0][2] = MFMA16(a0, b2_, facc[0][2]);
        facc[1][2] = MFMA16(a1, b2_, facc[1][2]);
        facc[2][2] = MFMA16(a2, b2_, facc[2][2]);
        facc[3][2] = MFMA16(a3, b2_, facc[3][2]);
        facc[0][3] = MFMA16(a0, b3, facc[0][3]);
        facc[1][3] = MFMA16(a1, b3, facc[1][3]);
        facc[2][3] = MFMA16(a2, b3, facc[2][3]);
        facc[3][3] = MFMA16(a3, b3, facc[3][3]);
      }
    }
    // ---- GELU -> H fp16 (swizzled; note the w*128 wave-column offset) ----
    #pragma unroll
    for (int nt = 0; nt < 4; ++nt) {
      const float bb = fb1[ch * 256 + w * 64 + nt * 16 + lr];
      #pragma unroll
      for (int tn = 0; tn < 4; ++tn) {
        #pragma unroll
        for (int r = 0; r < 4; ++r) {
          float a = facc[tn][nt][r] + bb;
          float gl = 0.5f * a * (1.f + erff(a * 0.70710678118654752f));
          const int tok = tn * 16 + lk * 4 + r;
          *(_Float16*)(smem + MH_OFF +
                       ((tok * 512 + w * 128 + nt * 32 + lr * 2) ^ ((tok & 7) << 4))) =
              (_Float16)gl;
        }
      }
    }
    __syncthreads();
    // ---- fc2 accumulate: oacc += H @ W2[ch*256.., w*64 + nt*16 + lr] ----
    {
      const _Float16* w2p = w2h + (size_t)(w * 64 + lr) * 1024 + ch * 256 + lk * 8;
      #pragma unroll
      for (int ks = 0; ks < 8; ++ks) {
        const int ko = ks * 64 + lk * 16;
        h8 a0 = *(const h8*)(smem + MH_OFF + (((0 * 16 + lr) * 512 + ko) ^ swz));
        h8 a1 = *(const h8*)(smem + MH_OFF + (((1 * 16 + lr) * 512 + ko) ^ swz));
        h8 a2 = *(const h8*)(smem + MH_OFF + (((2 * 16 + lr) * 512 + ko) ^ swz));
        h8 a3 = *(const h8*)(smem + MH_OFF + (((3 * 16 + lr) * 512 + ko) ^ swz));
        h8 b0 = *(const h8*)(w2p + 0 * 16 * 1024 + ks * 32);
        h8 b1 = *(const h8*)(w2p + 1 * 16 * 1024 + ks * 32);
        h8 b2_ = *(const h8*)(w2p + 2 * 16 * 1024 + ks * 32);
        h8 b3 = *(const h8*)(w2p + 3 * 16 * 1024 + ks * 32);
        oacc[0][0] = MFMA16(a0, b0, oacc[0][0]);
        oacc[1][0] = MFMA16(a1, b0, oacc[1][0]);
        oacc[2][0] = MFMA16(a2, b0, oacc[2][0]);
        oacc[3][0] = MFMA16(a3, b0, oacc[3][0]);
        oacc[0][1] = MFMA16(a0, b1, oacc[0][1]);
        oacc[1][1] = MFMA16(a1, b1, oacc[1][1]);
        oacc[2][1] = MFMA16(a2, b1, oacc[2][1]);
        oacc[3][1] = MFMA16(a3, b1, oacc[3][1]);
        oacc[0][2] = MFMA16(a0, b2_, oacc[0][2]);
        oacc[1][2] = MFMA16(a1, b2_, oacc[1][2]);
        oacc[2][2] = MFMA16(a2, b2_, oacc[2][2]);
        oacc[3][2] = MFMA16(a3, b2_, oacc[3][2]);
        oacc[0][3] = MFMA16(a0, b3, oacc[0][3]);
        oacc[1][3] = MFMA16(a1, b3, oacc[1][3]);
        oacc[2][3] = MFMA16(a2, b3, oacc[2][3]);
        oacc[3][3] = MFMA16(a3, b3, oacc[3][3]);
      }
    }
    __syncthreads();   // protect H before next chunk's GELU writes
  }

  // ---- epilogue: residual ----
  #pragma unroll
  for (int nt = 0; nt < 4; ++nt) {
    const float bv = fb2[w * 64 + nt * 16 + lr];
    #pragma unroll
    for (int tn = 0; tn < 4; ++tn) {
      #pragma unroll
      for (int r = 0; r < 4; ++r) {
        const int tok = tn * 16 + lk * 4 + r;
        const size_t idx = (t0 + tok) * 256 + (size_t)(w * 64 + nt * 16 + lr);
        io[idx] = io[idx] + oacc[tn][nt][r] + bv;
      }
    }
  }
}

extern "C" void kernel_launch(void* const* d_in, const int* in_sizes, int n_in,
                              void* d_out, int out_size, void* d_ws, size_t ws_size,
                              hipStream_t stream) {
  const float* x     = (const float*)d_in[0];
  const float* amask = (const float*)d_in[1];
  const float* g1    = (const float*)d_in[2];
  const float* b1    = (const float*)d_in[3];
  const float* qkvw  = (const float*)d_in[4];
  const float* qkvb  = (const float*)d_in[5];
  const float* temp  = (const float*)d_in[6];
  const float* rtab  = (const float*)d_in[7];
  const float* pw    = (const float*)d_in[8];
  const float* pb    = (const float*)d_in[9];
  const float* g2    = (const float*)d_in[10];
  const float* b2    = (const float*)d_in[11];
  const float* w1    = (const float*)d_in[12];
  const float* fb1   = (const float*)d_in[13];
  const float* w2    = (const float*)d_in[14];
  const float* fb2   = (const float*)d_in[15];
  const int* rpi     = (const int*)d_in[16];
  // d_in[17], d_in[18] = H, W (fixed 56)

  char* ws = (char*)d_ws;
  _Float16* wsq = (_Float16*)ws;               // 393,216 B (768x256 fp16)
  _Float16* pwh = (_Float16*)(ws + 393216);    // 131,072 B (256x256 fp16)
  _Float16* w1h = (_Float16*)(ws + 524288);    // 524,288 B (1024x256 fp16)
  _Float16* w2h = (_Float16*)(ws + 1048576);   // 524,288 B (256x1024 fp16)
  float* io = (float*)d_out;

  k_prep_qkv<<<768, 256, 0, stream>>>(qkvw, wsq);
  k_prep_pw<<<256, 256, 0, stream>>>(pw, pwh);
  k_prep_w1<<<1024, 256, 0, stream>>>(w1, w1h);
  k_prep_w2<<<1024, 256, 0, stream>>>(w2, w2h);
  k_attn<<<2048, 256, 0, stream>>>(x, wsq, pwh, qkvb, g1, b1, temp, rpi, rtab,
                                   amask, pb, io);
  k_mlp2<<<1568, 256, 0, stream>>>(io, g2, b2, w1h, fb1, w2h, fb2);
}

// Round 5
// 851.450 us; speedup vs baseline: 6.4562x; 1.4024x over previous
//
#include <hip/hip_runtime.h>

typedef unsigned short u16;
typedef unsigned int u32;
typedef _Float16 h4 __attribute__((ext_vector_type(4)));
typedef _Float16 h8 __attribute__((ext_vector_type(8)));
typedef float f32x4 __attribute__((ext_vector_type(4)));

#define MFMA16(a, b, c) __builtin_amdgcn_mfma_f32_16x16x32_f16((a), (b), (c), 0, 0, 0)

__device__ __forceinline__ float wsum(float v) {
  #pragma unroll
  for (int o = 32; o > 0; o >>= 1) v += __shfl_down(v, o);
  return __shfl(v, 0);
}

// ---------- prep: qkv_w f32 [256k][768c] -> fp16 [row = h*96 + mat*32 + cc][256 k] ----------
__global__ void k_prep_qkv(const float* __restrict__ w, _Float16* __restrict__ o) {
  const int e = blockIdx.x * 256 + threadIdx.x;   // 768*256
  const int r = e >> 8, k = e & 255;
  const int h = r / 96, rem = r - h * 96;
  const int mat = rem >> 5, cc = rem & 31;
  o[e] = (_Float16)w[k * 768 + mat * 256 + h * 32 + cc];
}

// ---------- prep: proj_w f32 [256 in][256 out] -> fp16 [out][in] (k-contiguous) ----------
__global__ void k_prep_pw(const float* __restrict__ w, _Float16* __restrict__ o) {
  const int e = blockIdx.x * 256 + threadIdx.x;   // 256*256
  const int oc = e >> 8, ic = e & 255;
  o[e] = (_Float16)w[ic * 256 + oc];
}

// ---------- prep: fc1_w f32 [256k][1024c] -> fp16 [col][256 k] ----------
__global__ void k_prep_w1(const float* __restrict__ w, _Float16* __restrict__ o) {
  const int e = blockIdx.x * 256 + threadIdx.x;   // 1024*256
  const int col = e >> 8, k = e & 255;
  o[e] = (_Float16)w[k * 1024 + col];
}

// ---------- prep: fc2_w f32 [1024k][256c] -> fp16 [col][1024 k] ----------
__global__ void k_prep_w2(const float* __restrict__ w, _Float16* __restrict__ o) {
  const int e = blockIdx.x * 256 + threadIdx.x;   // 256*1024
  const int oc = e >> 10, k = e & 1023;
  o[e] = (_Float16)w[k * 256 + oc];
}

// ---------- prep: btab[h][e] = rtab[rpi[e]*8 + h]  (folds the indirection) ----------
__global__ void k_prep_btab(const int* __restrict__ rpi, const float* __restrict__ rtab,
                            float* __restrict__ btab) {
  const int e = blockIdx.x * 256 + threadIdx.x;
  if (e < 2401) {
    const int idx = rpi[e];
    #pragma unroll
    for (int h = 0; h < 8; ++h) btab[h * 2401 + e] = rtab[idx * 8 + h];
  }
}

// ---------- K1: attention block, wave = head. 2048 blocks x 512 threads (8 waves). ----------
// LDS (128 KiB):
//   ZN  [0,32768)  : LN out fp16 [64 rows][512 B], swz ((row&7)<<4); rows 49-63 uninit
//                    (read in qkv A-frags, row-isolated, masked at D-write).
//                    After barrier 2, O fp16 [64][512 B] overlays this region (same swz).
//   per-wave W = 32768 + w*12288:
//     Q  W+0    [64 tok][64 B], byte = tok*64 + cc*2, swz ^(((tok>>1)&3)<<4)
//     K  W+4096 same layout
//     V  W+8192 token-chunked: (tok,cc) -> (tok>>3)*512 + cc*16 + (tok&7)*2
//     P  overlays W+0..8191: [64 n][128 B], byte = n*128 + m*2, swz ^((n&7)<<4)
__global__ __launch_bounds__(512, 2) void k_attn(
    const float* __restrict__ x, const _Float16* __restrict__ wsq,
    const _Float16* __restrict__ pwh, const float* __restrict__ qkvb,
    const float* __restrict__ g1, const float* __restrict__ b1,
    const float* __restrict__ temp, const float* __restrict__ btab,
    const float* __restrict__ amask, const float* __restrict__ pb,
    float* __restrict__ io) {
  __shared__ __align__(16) char smem[131072];
  const int tid = threadIdx.x;
  const int lane = tid & 63, w = tid >> 6;      // w = head index (0..7)
  const int lr = lane & 15, lk = lane >> 4;
  const int win = blockIdx.x;
  const int bb = win >> 6, wimg = win & 63;
  const int hb = wimg >> 3, wb = wimg & 7;
  const float scale = expf(temp[0]);
  char* const pwv = smem + 32768 + w * 12288;   // wave-private scratch

  // --- LN1 at shifted source coords (roll(-3)) -> ZN fp16 ---
  {
    const float4 gz = ((const float4*)g1)[lane];
    const float4 bz = ((const float4*)b1)[lane];
    for (int n = w; n < 49; n += 8) {
      int i = n / 7, j = n - 7 * i;
      int rs = hb * 7 + i + 3; if (rs >= 56) rs -= 56;
      int cs = wb * 7 + j + 3; if (cs >= 56) cs -= 56;
      const float4 p = ((const float4*)(x + ((size_t)bb * 3136 + rs * 56 + cs) * 256))[lane];
      float mean = wsum(p.x + p.y + p.z + p.w) * (1.f / 256.f);
      float d0 = p.x - mean, d1 = p.y - mean, d2 = p.z - mean, d3 = p.w - mean;
      float var = wsum(d0 * d0 + d1 * d1 + d2 * d2 + d3 * d3) * (1.f / 256.f);
      float rstd = rsqrtf(var + 1e-6f);
      h4 z;
      z[0] = (_Float16)(d0 * rstd * gz.x + bz.x);
      z[1] = (_Float16)(d1 * rstd * gz.y + bz.y);
      z[2] = (_Float16)(d2 * rstd * gz.z + bz.z);
      z[3] = (_Float16)(d3 * rstd * gz.w + bz.w);
      *(h4*)(smem + ((n * 512 + lane * 8) ^ ((n & 7) << 4))) = z;
    }
  }
  __syncthreads();   // barrier 1: ZN ready

  // ---- qkv for head w: (64x256)@(256x96), 192 MFMA ----
  {
    f32x4 zz = {0.f, 0.f, 0.f, 0.f};
    f32x4 acc[4][6];
    #pragma unroll
    for (int t = 0; t < 4; ++t)
      #pragma unroll
      for (int c = 0; c < 6; ++c) acc[t][c] = zz;
    const _Float16* wr[6];
    #pragma unroll
    for (int c = 0; c < 6; ++c)
      wr[c] = wsq + ((size_t)(w * 96 + c * 16 + lr) * 256 + lk * 8);
    const int swzA = (lr & 7) << 4;
    #pragma unroll
    for (int ks = 0; ks < 8; ++ks) {
      const int ko = ks * 64 + lk * 16;
      h8 a[4];
      #pragma unroll
      for (int t = 0; t < 4; ++t)
        a[t] = *(const h8*)(smem + (((t * 16 + lr) * 512 + ko) ^ swzA));
      h8 b[6];
      #pragma unroll
      for (int c = 0; c < 6; ++c) b[c] = *(const h8*)(wr[c] + ks * 32);
      #pragma unroll
      for (int t = 0; t < 4; ++t)
        #pragma unroll
        for (int c = 0; c < 6; ++c) acc[t][c] = MFMA16(a[t], b[c], acc[t][c]);
    }
    // D -> Q/K/V (pad tokens >=49 written as 0)
    #pragma unroll
    for (int c = 0; c < 6; ++c) {
      const int mat = c >> 1;
      const int cc = (c & 1) * 16 + lr;
      const float bias = qkvb[mat * 256 + w * 32 + cc];
      #pragma unroll
      for (int t = 0; t < 4; ++t) {
        const int tok0 = t * 16 + lk * 4;
        if (mat == 2) {
          h4 pk;
          #pragma unroll
          for (int r = 0; r < 4; ++r) {
            float v = (tok0 + r < 49) ? (acc[t][c][r] + bias) : 0.f;
            pk[r] = (_Float16)v;
          }
          *(h4*)(pwv + 8192 + (tok0 >> 3) * 512 + cc * 16 + (tok0 & 7) * 2) = pk;
        } else {
          char* base = pwv + (mat ? 4096 : 0);
          const float mult = mat ? 1.f : scale;   // fold exp(temperature) into q
          #pragma unroll
          for (int r = 0; r < 4; ++r) {
            const int tok = tok0 + r;
            float v = (tok < 49) ? (acc[t][c][r] + bias) * mult : 0.f;
            *(_Float16*)(base + ((tok * 64 + cc * 2) ^ (((tok >> 1) & 3) << 4))) = (_Float16)v;
          }
        }
      }
    }
  }
  __syncthreads();   // barrier 2: all ZN reads done -> O may overlay ZN

  // ---- scores (16 MFMA) + in-register softmax -> P (overlays Q/K) ----
  {
    f32x4 zz = {0.f, 0.f, 0.f, 0.f};
    f32x4 s[4][4];
    #pragma unroll
    for (int t = 0; t < 4; ++t)
      #pragma unroll
      for (int m = 0; m < 4; ++m) s[t][m] = zz;
    const int swzq = ((lr >> 1) & 3) << 4;
    h8 aq[4], bk[4];
    #pragma unroll
    for (int t = 0; t < 4; ++t) {
      aq[t] = *(const h8*)(pwv + (((t * 16 + lr) * 64 + lk * 16) ^ swzq));
      bk[t] = *(const h8*)(pwv + 4096 + (((t * 16 + lr) * 64 + lk * 16) ^ swzq));
    }
    #pragma unroll
    for (int t = 0; t < 4; ++t)
      #pragma unroll
      for (int m = 0; m < 4; ++m) s[t][m] = MFMA16(aq[t], bk[m], s[t][m]);

    // diag(-1e30 pre-bias, per ref) + rel-pos bias + shift mask; cols>=49 -> -inf; rows>=49 -> 0
    const float* bt = btab + (size_t)w * 2401;
    const float* am = amask + (size_t)wimg * 2401;
    #pragma unroll
    for (int t = 0; t < 4; ++t) {
      #pragma unroll
      for (int r = 0; r < 4; ++r) {
        const int n = t * 16 + lk * 4 + r;
        if (n < 49) {
          #pragma unroll
          for (int m = 0; m < 4; ++m) {
            const int mm = m * 16 + lr;
            float sv;
            if (mm >= 49) sv = -1e38f;
            else {
              sv = s[t][m][r];
              if (mm == n) sv = -1e30f;
              const int ee = n * 49 + mm;
              sv += bt[ee] + am[ee];
            }
            s[t][m][r] = sv;
          }
        } else {
          #pragma unroll
          for (int m = 0; m < 4; ++m) s[t][m][r] = 0.f;   // finite garbage row, never stored
        }
      }
    }
    // softmax: row n lives on the 16 lanes sharing lk -> shfl_xor {1,2,4,8}
    #pragma unroll
    for (int t = 0; t < 4; ++t) {
      #pragma unroll
      for (int r = 0; r < 4; ++r) {
        float mx = fmaxf(fmaxf(s[t][0][r], s[t][1][r]), fmaxf(s[t][2][r], s[t][3][r]));
        mx = fmaxf(mx, __shfl_xor(mx, 1));
        mx = fmaxf(mx, __shfl_xor(mx, 2));
        mx = fmaxf(mx, __shfl_xor(mx, 4));
        mx = fmaxf(mx, __shfl_xor(mx, 8));
        float e0 = expf(s[t][0][r] - mx), e1 = expf(s[t][1][r] - mx);
        float e2 = expf(s[t][2][r] - mx), e3 = expf(s[t][3][r] - mx);
        float sm = e0 + e1 + e2 + e3;
        sm += __shfl_xor(sm, 1);
        sm += __shfl_xor(sm, 2);
        sm += __shfl_xor(sm, 4);
        sm += __shfl_xor(sm, 8);
        const float inv = 1.f / sm;
        const int n = t * 16 + lk * 4 + r;
        const int sw = (n & 7) << 4;
        char* pr = pwv + n * 128;
        *(_Float16*)(pr + ((lr * 2) ^ sw))          = (_Float16)(e0 * inv);
        *(_Float16*)(pr + (((16 + lr) * 2) ^ sw))   = (_Float16)(e1 * inv);
        *(_Float16*)(pr + (((32 + lr) * 2) ^ sw))   = (_Float16)(e2 * inv);
        *(_Float16*)(pr + (((48 + lr) * 2) ^ sw))   = (_Float16)(e3 * inv);
      }
    }
  }

  // ---- PV (16 MFMA) -> O slice (ch w*32..w*32+32) into shared O (ZN region) ----
  {
    f32x4 zz = {0.f, 0.f, 0.f, 0.f};
    f32x4 o0[4], o1[4];
    #pragma unroll
    for (int t = 0; t < 4; ++t) { o0[t] = zz; o1[t] = zz; }
    const int swzp = (lr & 7) << 4;
    #pragma unroll
    for (int ks = 0; ks < 2; ++ks) {
      h8 bv0 = *(const h8*)(pwv + 8192 + (ks * 4 + lk) * 512 + lr * 16);
      h8 bv1 = *(const h8*)(pwv + 8192 + (ks * 4 + lk) * 512 + (16 + lr) * 16);
      #pragma unroll
      for (int t = 0; t < 4; ++t) {
        h8 ap = *(const h8*)(pwv + (((t * 16 + lr) * 128 + ks * 64 + lk * 16) ^ swzp));
        o0[t] = MFMA16(ap, bv0, o0[t]);
        o1[t] = MFMA16(ap, bv1, o1[t]);
      }
    }
    #pragma unroll
    for (int t = 0; t < 4; ++t) {
      #pragma unroll
      for (int r = 0; r < 4; ++r) {
        const int tok = t * 16 + lk * 4 + r;
        const int sw = (tok & 7) << 4;
        char* orow = smem + tok * 512;
        *(_Float16*)(orow + (((w * 32 + lr) * 2) ^ sw))      = (_Float16)o0[t][r];
        *(_Float16*)(orow + (((w * 32 + 16 + lr) * 2) ^ sw)) = (_Float16)o1[t][r];
      }
    }
  }
  __syncthreads();   // barrier 3: full O ready

  // ---- proj: out cols w*32 .. +32, K=256 (64 MFMA) + reverse shift + residual ----
  {
    f32x4 zz = {0.f, 0.f, 0.f, 0.f};
    f32x4 oacc[4][2];
    #pragma unroll
    for (int t = 0; t < 4; ++t) { oacc[t][0] = zz; oacc[t][1] = zz; }
    const int swzA = (lr & 7) << 4;
    const _Float16* pwr = pwh + (size_t)(w * 32 + lr) * 256 + lk * 8;
    #pragma unroll
    for (int ks = 0; ks < 8; ++ks) {
      const int ko = ks * 64 + lk * 16;
      h8 b0 = *(const h8*)(pwr + ks * 32);
      h8 b1 = *(const h8*)(pwr + 16 * 256 + ks * 32);
      #pragma unroll
      for (int t = 0; t < 4; ++t) {
        h8 a = *(const h8*)(smem + (((t * 16 + lr) * 512 + ko) ^ swzA));
        oacc[t][0] = MFMA16(a, b0, oacc[t][0]);
        oacc[t][1] = MFMA16(a, b1, oacc[t][1]);
      }
    }
    const float pb0 = pb[w * 32 + lr];
    const float pb1 = pb[w * 32 + 16 + lr];
    #pragma unroll
    for (int t = 0; t < 4; ++t) {
      #pragma unroll
      for (int r = 0; r < 4; ++r) {
        const int tok = t * 16 + lk * 4 + r;
        if (tok < 49) {
          const int i = tok / 7, j = tok - 7 * i;
          int rs = hb * 7 + i + 3; if (rs >= 56) rs -= 56;
          int cs = wb * 7 + j + 3; if (cs >= 56) cs -= 56;
          const size_t ro = ((size_t)bb * 3136 + rs * 56 + cs) * 256 + w * 32 + lr;
          io[ro]      = x[ro]      + oacc[t][0][r] + pb0;
          io[ro + 16] = x[ro + 16] + oacc[t][1][r] + pb1;
        }
      }
    }
  }
}

// ---------- K2: LN2 + fc1 + GELU + fc2 + residual via MFMA ----------
// 64 tokens/block (1568 blocks), 512 threads = 8 waves, 64 KiB LDS -> 2 blocks/CU.
#define MH_OFF 32768

__global__ __launch_bounds__(512, 4) void k_mlp2(
    float* __restrict__ io, const float* __restrict__ g2, const float* __restrict__ b2,
    const _Float16* __restrict__ w1h, const float* __restrict__ fb1,
    const _Float16* __restrict__ w2h, const float* __restrict__ fb2) {
  __shared__ __align__(16) char smem[65536];
  const int tid = threadIdx.x;
  const int lane = tid & 63, w = tid >> 6;
  const int lr = lane & 15, lk = lane >> 4;
  const size_t t0 = (size_t)blockIdx.x * 64;
  const int swz = (lr & 7) << 4;

  // --- LN2 -> ZN fp16 ---
  {
    const float4 gz = ((const float4*)g2)[lane];
    const float4 bz = ((const float4*)b2)[lane];
    for (int n = w; n < 64; n += 8) {
      const float4 p = ((const float4*)(io + (t0 + n) * 256))[lane];
      float mean = wsum(p.x + p.y + p.z + p.w) * (1.f / 256.f);
      float d0 = p.x - mean, d1 = p.y - mean, d2 = p.z - mean, d3 = p.w - mean;
      float var = wsum(d0 * d0 + d1 * d1 + d2 * d2 + d3 * d3) * (1.f / 256.f);
      float rstd = rsqrtf(var + 1e-6f);
      h4 z;
      z[0] = (_Float16)(d0 * rstd * gz.x + bz.x);
      z[1] = (_Float16)(d1 * rstd * gz.y + bz.y);
      z[2] = (_Float16)(d2 * rstd * gz.z + bz.z);
      z[3] = (_Float16)(d3 * rstd * gz.w + bz.w);
      *(h4*)(smem + ((n * 512 + lane * 8) ^ ((n & 7) << 4))) = z;
    }
  }
  __syncthreads();

  f32x4 zz = {0.f, 0.f, 0.f, 0.f};
  f32x4 oacc[4][2];   // out col = w*32 + nt*16 + lr, tok = tn*16 + lk*4 + r
  #pragma unroll
  for (int t = 0; t < 4; ++t) { oacc[t][0] = zz; oacc[t][1] = zz; }

  for (int ch = 0; ch < 4; ++ch) {
    // ---- fc1 chunk: F = ZN @ W1[:, ch*256 + w*32 .. +32) ----
    f32x4 facc[4][2];
    #pragma unroll
    for (int t = 0; t < 4; ++t) { facc[t][0] = zz; facc[t][1] = zz; }
    {
      const _Float16* w1p = w1h + (size_t)(ch * 256 + w * 32 + lr) * 256 + lk * 8;
      #pragma unroll
      for (int ks = 0; ks < 8; ++ks) {
        const int ko = ks * 64 + lk * 16;
        h8 b0 = *(const h8*)(w1p + ks * 32);
        h8 b1 = *(const h8*)(w1p + 16 * 256 + ks * 32);
        #pragma unroll
        for (int t = 0; t < 4; ++t) {
          h8 a = *(const h8*)(smem + (((t * 16 + lr) * 512 + ko) ^ swz));
          facc[t][0] = MFMA16(a, b0, facc[t][0]);
          facc[t][1] = MFMA16(a, b1, facc[t][1]);
        }
      }
    }
    // ---- GELU -> H fp16 (col = w*32 + nt*16 + lr -> byte w*64 + nt*32 + lr*2) ----
    #pragma unroll
    for (int nt = 0; nt < 2; ++nt) {
      const float bb = fb1[ch * 256 + w * 32 + nt * 16 + lr];
      #pragma unroll
      for (int t = 0; t < 4; ++t) {
        #pragma unroll
        for (int r = 0; r < 4; ++r) {
          float a = facc[t][nt][r] + bb;
          float gl = 0.5f * a * (1.f + erff(a * 0.70710678118654752f));
          const int tok = t * 16 + lk * 4 + r;
          *(_Float16*)(smem + MH_OFF +
                       ((tok * 512 + w * 64 + nt * 32 + lr * 2) ^ ((tok & 7) << 4))) =
              (_Float16)gl;
        }
      }
    }
    __syncthreads();
    // ---- fc2 accumulate: oacc += H @ W2[ch*256.., w*32 + nt*16 + lr] ----
    {
      const _Float16* w2p = w2h + (size_t)(w * 32 + lr) * 1024 + ch * 256 + lk * 8;
      #pragma unroll
      for (int ks = 0; ks < 8; ++ks) {
        const int ko = ks * 64 + lk * 16;
        h8 b0 = *(const h8*)(w2p + ks * 32);
        h8 b1 = *(const h8*)(w2p + 16 * 1024 + ks * 32);
        #pragma unroll
        for (int t = 0; t < 4; ++t) {
          h8 a = *(const h8*)(smem + MH_OFF + (((t * 16 + lr) * 512 + ko) ^ swz));
          oacc[t][0] = MFMA16(a, b0, oacc[t][0]);
          oacc[t][1] = MFMA16(a, b1, oacc[t][1]);
        }
      }
    }
    __syncthreads();   // protect H before next chunk's GELU writes
  }

  // ---- epilogue: residual ----
  #pragma unroll
  for (int nt = 0; nt < 2; ++nt) {
    const float bv = fb2[w * 32 + nt * 16 + lr];
    #pragma unroll
    for (int t = 0; t < 4; ++t) {
      #pragma unroll
      for (int r = 0; r < 4; ++r) {
        const int tok = t * 16 + lk * 4 + r;
        const size_t idx = (t0 + tok) * 256 + (size_t)(w * 32 + nt * 16 + lr);
        io[idx] = io[idx] + oacc[t][nt][r] + bv;
      }
    }
  }
}

extern "C" void kernel_launch(void* const* d_in, const int* in_sizes, int n_in,
                              void* d_out, int out_size, void* d_ws, size_t ws_size,
                              hipStream_t stream) {
  const float* x     = (const float*)d_in[0];
  const float* amask = (const float*)d_in[1];
  const float* g1    = (const float*)d_in[2];
  const float* b1    = (const float*)d_in[3];
  const float* qkvw  = (const float*)d_in[4];
  const float* qkvb  = (const float*)d_in[5];
  const float* temp  = (const float*)d_in[6];
  const float* rtab  = (const float*)d_in[7];
  const float* pw    = (const float*)d_in[8];
  const float* pb    = (const float*)d_in[9];
  const float* g2    = (const float*)d_in[10];
  const float* b2    = (const float*)d_in[11];
  const float* w1    = (const float*)d_in[12];
  const float* fb1   = (const float*)d_in[13];
  const float* w2    = (const float*)d_in[14];
  const float* fb2   = (const float*)d_in[15];
  const int* rpi     = (const int*)d_in[16];
  // d_in[17], d_in[18] = H, W (fixed 56)

  char* ws = (char*)d_ws;
  _Float16* wsq = (_Float16*)ws;               // 393,216 B (768x256 fp16)
  _Float16* pwh = (_Float16*)(ws + 393216);    // 131,072 B (256x256 fp16)
  _Float16* w1h = (_Float16*)(ws + 524288);    //  524,288 B (1024x256 fp16)
  _Float16* w2h = (_Float16*)(ws + 1048576);   //  524,288 B (256x1024 fp16)
  float* btab   = (float*)(ws + 1572864);      //   76,832 B (8x2401 f32)
  float* io = (float*)d_out;

  k_prep_qkv<<<768, 256, 0, stream>>>(qkvw, wsq);
  k_prep_pw<<<256, 256, 0, stream>>>(pw, pwh);
  k_prep_w1<<<1024, 256, 0, stream>>>(w1, w1h);
  k_prep_w2<<<1024, 256, 0, stream>>>(w2, w2h);
  k_prep_btab<<<10, 256, 0, stream>>>(rpi, rtab, btab);
  k_attn<<<2048, 512, 0, stream>>>(x, wsq, pwh, qkvb, g1, b1, temp, btab,
                                   amask, pb, io);
  k_mlp2<<<1568, 512, 0, stream>>>(io, g2, b2, w1h, fb1, w2h, fb2);
}

// Round 6
// 816.775 us; speedup vs baseline: 6.7303x; 1.0425x over previous
//
#include <hip/hip_runtime.h>

typedef unsigned short u16;
typedef unsigned int u32;
typedef _Float16 h4 __attribute__((ext_vector_type(4)));
typedef _Float16 h8 __attribute__((ext_vector_type(8)));
typedef float f32x4 __attribute__((ext_vector_type(4)));

#define MFMA16(a, b, c) __builtin_amdgcn_mfma_f32_16x16x32_f16((a), (b), (c), 0, 0, 0)

__device__ __forceinline__ float wsum(float v) {
  #pragma unroll
  for (int o = 32; o > 0; o >>= 1) v += __shfl_down(v, o);
  return __shfl(v, 0);
}

// ---------- prep: qkv_w f32 [256k][768c] -> fp16 [row = h*96 + mat*32 + cc][256 k] ----------
__global__ void k_prep_qkv(const float* __restrict__ w, _Float16* __restrict__ o) {
  const int e = blockIdx.x * 256 + threadIdx.x;   // 768*256
  const int r = e >> 8, k = e & 255;
  const int h = r / 96, rem = r - h * 96;
  const int mat = rem >> 5, cc = rem & 31;
  o[e] = (_Float16)w[k * 768 + mat * 256 + h * 32 + cc];
}

// ---------- prep: proj_w f32 [256 in][256 out] -> fp16 [out][in] (k-contiguous) ----------
__global__ void k_prep_pw(const float* __restrict__ w, _Float16* __restrict__ o) {
  const int e = blockIdx.x * 256 + threadIdx.x;   // 256*256
  const int oc = e >> 8, ic = e & 255;
  o[e] = (_Float16)w[ic * 256 + oc];
}

// ---------- prep: fc1_w f32 [256k][1024c] -> fp16 [col][256 k] ----------
__global__ void k_prep_w1(const float* __restrict__ w, _Float16* __restrict__ o) {
  const int e = blockIdx.x * 256 + threadIdx.x;   // 1024*256
  const int col = e >> 8, k = e & 255;
  o[e] = (_Float16)w[k * 1024 + col];
}

// ---------- prep: fc2_w f32 [1024k][256c] -> fp16 [col][1024 k] ----------
__global__ void k_prep_w2(const float* __restrict__ w, _Float16* __restrict__ o) {
  const int e = blockIdx.x * 256 + threadIdx.x;   // 256*1024
  const int oc = e >> 10, k = e & 1023;
  o[e] = (_Float16)w[k * 256 + oc];
}

// ---------- prep: btab[h][e] = rtab[rpi[e]*8 + h]  (folds the indirection) ----------
__global__ void k_prep_btab(const int* __restrict__ rpi, const float* __restrict__ rtab,
                            float* __restrict__ btab) {
  const int e = blockIdx.x * 256 + threadIdx.x;
  if (e < 2401) {
    const int idx = rpi[e];
    #pragma unroll
    for (int h = 0; h < 8; ++h) btab[h * 2401 + e] = rtab[idx * 8 + h];
  }
}

// ---------- K1: attention block, wave = head. 2048 blocks x 512 threads (8 waves). ----------
// (unchanged from round 5 — verified at ~420 us; target next round with fresh counters)
__global__ __launch_bounds__(512, 2) void k_attn(
    const float* __restrict__ x, const _Float16* __restrict__ wsq,
    const _Float16* __restrict__ pwh, const float* __restrict__ qkvb,
    const float* __restrict__ g1, const float* __restrict__ b1,
    const float* __restrict__ temp, const float* __restrict__ btab,
    const float* __restrict__ amask, const float* __restrict__ pb,
    float* __restrict__ io) {
  __shared__ __align__(16) char smem[131072];
  const int tid = threadIdx.x;
  const int lane = tid & 63, w = tid >> 6;      // w = head index (0..7)
  const int lr = lane & 15, lk = lane >> 4;
  const int win = blockIdx.x;
  const int bb = win >> 6, wimg = win & 63;
  const int hb = wimg >> 3, wb = wimg & 7;
  const float scale = expf(temp[0]);
  char* const pwv = smem + 32768 + w * 12288;   // wave-private scratch

  // --- LN1 at shifted source coords (roll(-3)) -> ZN fp16 ---
  {
    const float4 gz = ((const float4*)g1)[lane];
    const float4 bz = ((const float4*)b1)[lane];
    for (int n = w; n < 49; n += 8) {
      int i = n / 7, j = n - 7 * i;
      int rs = hb * 7 + i + 3; if (rs >= 56) rs -= 56;
      int cs = wb * 7 + j + 3; if (cs >= 56) cs -= 56;
      const float4 p = ((const float4*)(x + ((size_t)bb * 3136 + rs * 56 + cs) * 256))[lane];
      float mean = wsum(p.x + p.y + p.z + p.w) * (1.f / 256.f);
      float d0 = p.x - mean, d1 = p.y - mean, d2 = p.z - mean, d3 = p.w - mean;
      float var = wsum(d0 * d0 + d1 * d1 + d2 * d2 + d3 * d3) * (1.f / 256.f);
      float rstd = rsqrtf(var + 1e-6f);
      h4 z;
      z[0] = (_Float16)(d0 * rstd * gz.x + bz.x);
      z[1] = (_Float16)(d1 * rstd * gz.y + bz.y);
      z[2] = (_Float16)(d2 * rstd * gz.z + bz.z);
      z[3] = (_Float16)(d3 * rstd * gz.w + bz.w);
      *(h4*)(smem + ((n * 512 + lane * 8) ^ ((n & 7) << 4))) = z;
    }
  }
  __syncthreads();   // barrier 1: ZN ready

  // ---- qkv for head w: (64x256)@(256x96), 192 MFMA ----
  {
    f32x4 zz = {0.f, 0.f, 0.f, 0.f};
    f32x4 acc[4][6];
    #pragma unroll
    for (int t = 0; t < 4; ++t)
      #pragma unroll
      for (int c = 0; c < 6; ++c) acc[t][c] = zz;
    const _Float16* wr[6];
    #pragma unroll
    for (int c = 0; c < 6; ++c)
      wr[c] = wsq + ((size_t)(w * 96 + c * 16 + lr) * 256 + lk * 8);
    const int swzA = (lr & 7) << 4;
    #pragma unroll
    for (int ks = 0; ks < 8; ++ks) {
      const int ko = ks * 64 + lk * 16;
      h8 a[4];
      #pragma unroll
      for (int t = 0; t < 4; ++t)
        a[t] = *(const h8*)(smem + (((t * 16 + lr) * 512 + ko) ^ swzA));
      h8 b[6];
      #pragma unroll
      for (int c = 0; c < 6; ++c) b[c] = *(const h8*)(wr[c] + ks * 32);
      #pragma unroll
      for (int t = 0; t < 4; ++t)
        #pragma unroll
        for (int c = 0; c < 6; ++c) acc[t][c] = MFMA16(a[t], b[c], acc[t][c]);
    }
    // D -> Q/K/V (pad tokens >=49 written as 0)
    #pragma unroll
    for (int c = 0; c < 6; ++c) {
      const int mat = c >> 1;
      const int cc = (c & 1) * 16 + lr;
      const float bias = qkvb[mat * 256 + w * 32 + cc];
      #pragma unroll
      for (int t = 0; t < 4; ++t) {
        const int tok0 = t * 16 + lk * 4;
        if (mat == 2) {
          h4 pk;
          #pragma unroll
          for (int r = 0; r < 4; ++r) {
            float v = (tok0 + r < 49) ? (acc[t][c][r] + bias) : 0.f;
            pk[r] = (_Float16)v;
          }
          *(h4*)(pwv + 8192 + (tok0 >> 3) * 512 + cc * 16 + (tok0 & 7) * 2) = pk;
        } else {
          char* base = pwv + (mat ? 4096 : 0);
          const float mult = mat ? 1.f : scale;   // fold exp(temperature) into q
          #pragma unroll
          for (int r = 0; r < 4; ++r) {
            const int tok = tok0 + r;
            float v = (tok < 49) ? (acc[t][c][r] + bias) * mult : 0.f;
            *(_Float16*)(base + ((tok * 64 + cc * 2) ^ (((tok >> 1) & 3) << 4))) = (_Float16)v;
          }
        }
      }
    }
  }
  __syncthreads();   // barrier 2: all ZN reads done -> O may overlay ZN

  // ---- scores (16 MFMA) + in-register softmax -> P (overlays Q/K) ----
  {
    f32x4 zz = {0.f, 0.f, 0.f, 0.f};
    f32x4 s[4][4];
    #pragma unroll
    for (int t = 0; t < 4; ++t)
      #pragma unroll
      for (int m = 0; m < 4; ++m) s[t][m] = zz;
    const int swzq = ((lr >> 1) & 3) << 4;
    h8 aq[4], bk[4];
    #pragma unroll
    for (int t = 0; t < 4; ++t) {
      aq[t] = *(const h8*)(pwv + (((t * 16 + lr) * 64 + lk * 16) ^ swzq));
      bk[t] = *(const h8*)(pwv + 4096 + (((t * 16 + lr) * 64 + lk * 16) ^ swzq));
    }
    #pragma unroll
    for (int t = 0; t < 4; ++t)
      #pragma unroll
      for (int m = 0; m < 4; ++m) s[t][m] = MFMA16(aq[t], bk[m], s[t][m]);

    // diag(-1e30 pre-bias, per ref) + rel-pos bias + shift mask; cols>=49 -> -inf; rows>=49 -> 0
    const float* bt = btab + (size_t)w * 2401;
    const float* am = amask + (size_t)wimg * 2401;
    #pragma unroll
    for (int t = 0; t < 4; ++t) {
      #pragma unroll
      for (int r = 0; r < 4; ++r) {
        const int n = t * 16 + lk * 4 + r;
        if (n < 49) {
          #pragma unroll
          for (int m = 0; m < 4; ++m) {
            const int mm = m * 16 + lr;
            float sv;
            if (mm >= 49) sv = -1e38f;
            else {
              sv = s[t][m][r];
              if (mm == n) sv = -1e30f;
              const int ee = n * 49 + mm;
              sv += bt[ee] + am[ee];
            }
            s[t][m][r] = sv;
          }
        } else {
          #pragma unroll
          for (int m = 0; m < 4; ++m) s[t][m][r] = 0.f;   // finite garbage row, never stored
        }
      }
    }
    // softmax: row n lives on the 16 lanes sharing lk -> shfl_xor {1,2,4,8}
    #pragma unroll
    for (int t = 0; t < 4; ++t) {
      #pragma unroll
      for (int r = 0; r < 4; ++r) {
        float mx = fmaxf(fmaxf(s[t][0][r], s[t][1][r]), fmaxf(s[t][2][r], s[t][3][r]));
        mx = fmaxf(mx, __shfl_xor(mx, 1));
        mx = fmaxf(mx, __shfl_xor(mx, 2));
        mx = fmaxf(mx, __shfl_xor(mx, 4));
        mx = fmaxf(mx, __shfl_xor(mx, 8));
        float e0 = expf(s[t][0][r] - mx), e1 = expf(s[t][1][r] - mx);
        float e2 = expf(s[t][2][r] - mx), e3 = expf(s[t][3][r] - mx);
        float sm = e0 + e1 + e2 + e3;
        sm += __shfl_xor(sm, 1);
        sm += __shfl_xor(sm, 2);
        sm += __shfl_xor(sm, 4);
        sm += __shfl_xor(sm, 8);
        const float inv = 1.f / sm;
        const int n = t * 16 + lk * 4 + r;
        const int sw = (n & 7) << 4;
        char* pr = pwv + n * 128;
        *(_Float16*)(pr + ((lr * 2) ^ sw))          = (_Float16)(e0 * inv);
        *(_Float16*)(pr + (((16 + lr) * 2) ^ sw))   = (_Float16)(e1 * inv);
        *(_Float16*)(pr + (((32 + lr) * 2) ^ sw))   = (_Float16)(e2 * inv);
        *(_Float16*)(pr + (((48 + lr) * 2) ^ sw))   = (_Float16)(e3 * inv);
      }
    }
  }

  // ---- PV (16 MFMA) -> O slice (ch w*32..w*32+32) into shared O (ZN region) ----
  {
    f32x4 zz = {0.f, 0.f, 0.f, 0.f};
    f32x4 o0[4], o1[4];
    #pragma unroll
    for (int t = 0; t < 4; ++t) { o0[t] = zz; o1[t] = zz; }
    const int swzp = (lr & 7) << 4;
    #pragma unroll
    for (int ks = 0; ks < 2; ++ks) {
      h8 bv0 = *(const h8*)(pwv + 8192 + (ks * 4 + lk) * 512 + lr * 16);
      h8 bv1 = *(const h8*)(pwv + 8192 + (ks * 4 + lk) * 512 + (16 + lr) * 16);
      #pragma unroll
      for (int t = 0; t < 4; ++t) {
        h8 ap = *(const h8*)(pwv + (((t * 16 + lr) * 128 + ks * 64 + lk * 16) ^ swzp));
        o0[t] = MFMA16(ap, bv0, o0[t]);
        o1[t] = MFMA16(ap, bv1, o1[t]);
      }
    }
    #pragma unroll
    for (int t = 0; t < 4; ++t) {
      #pragma unroll
      for (int r = 0; r < 4; ++r) {
        const int tok = t * 16 + lk * 4 + r;
        const int sw = (tok & 7) << 4;
        char* orow = smem + tok * 512;
        *(_Float16*)(orow + (((w * 32 + lr) * 2) ^ sw))      = (_Float16)o0[t][r];
        *(_Float16*)(orow + (((w * 32 + 16 + lr) * 2) ^ sw)) = (_Float16)o1[t][r];
      }
    }
  }
  __syncthreads();   // barrier 3: full O ready

  // ---- proj: out cols w*32 .. +32, K=256 (64 MFMA) + reverse shift + residual ----
  {
    f32x4 zz = {0.f, 0.f, 0.f, 0.f};
    f32x4 oacc[4][2];
    #pragma unroll
    for (int t = 0; t < 4; ++t) { oacc[t][0] = zz; oacc[t][1] = zz; }
    const int swzA = (lr & 7) << 4;
    const _Float16* pwr = pwh + (size_t)(w * 32 + lr) * 256 + lk * 8;
    #pragma unroll
    for (int ks = 0; ks < 8; ++ks) {
      const int ko = ks * 64 + lk * 16;
      h8 b0 = *(const h8*)(pwr + ks * 32);
      h8 b1 = *(const h8*)(pwr + 16 * 256 + ks * 32);
      #pragma unroll
      for (int t = 0; t < 4; ++t) {
        h8 a = *(const h8*)(smem + (((t * 16 + lr) * 512 + ko) ^ swzA));
        oacc[t][0] = MFMA16(a, b0, oacc[t][0]);
        oacc[t][1] = MFMA16(a, b1, oacc[t][1]);
      }
    }
    const float pb0 = pb[w * 32 + lr];
    const float pb1 = pb[w * 32 + 16 + lr];
    #pragma unroll
    for (int t = 0; t < 4; ++t) {
      #pragma unroll
      for (int r = 0; r < 4; ++r) {
        const int tok = t * 16 + lk * 4 + r;
        if (tok < 49) {
          const int i = tok / 7, j = tok - 7 * i;
          int rs = hb * 7 + i + 3; if (rs >= 56) rs -= 56;
          int cs = wb * 7 + j + 3; if (cs >= 56) cs -= 56;
          const size_t ro = ((size_t)bb * 3136 + rs * 56 + cs) * 256 + w * 32 + lr;
          io[ro]      = x[ro]      + oacc[t][0][r] + pb0;
          io[ro + 16] = x[ro + 16] + oacc[t][1][r] + pb1;
        }
      }
    }
  }
}

// ---------- K2: LN2 + fc1 + GELU + fc2 + residual via MFMA ----------
// 64 tokens/block (1568 blocks), 512 threads = 8 waves, 64 KiB LDS -> 2 blocks/CU.
// launch_bounds(512,2): VGPR cap 256 (compiler lands ~100-128; (512,4) caused a 64-VGPR
// squeeze that spilled facc/oacc to scratch: WRITE_SIZE 326 MB vs 103 ideal).
// Epilogue: stage oacc f32 into dead ZN+H (exactly 64 KiB), then fully-coalesced float4
// read-modify-write of io in LN2 ordering.
#define MH_OFF 32768

__global__ __launch_bounds__(512, 2) void k_mlp2(
    float* __restrict__ io, const float* __restrict__ g2, const float* __restrict__ b2,
    const _Float16* __restrict__ w1h, const float* __restrict__ fb1,
    const _Float16* __restrict__ w2h, const float* __restrict__ fb2) {
  __shared__ __align__(16) char smem[65536];
  const int tid = threadIdx.x;
  const int lane = tid & 63, w = tid >> 6;
  const int lr = lane & 15, lk = lane >> 4;
  const size_t t0 = (size_t)blockIdx.x * 64;
  const int swz = (lr & 7) << 4;

  // --- LN2 -> ZN fp16 ---
  {
    const float4 gz = ((const float4*)g2)[lane];
    const float4 bz = ((const float4*)b2)[lane];
    for (int n = w; n < 64; n += 8) {
      const float4 p = ((const float4*)(io + (t0 + n) * 256))[lane];
      float mean = wsum(p.x + p.y + p.z + p.w) * (1.f / 256.f);
      float d0 = p.x - mean, d1 = p.y - mean, d2 = p.z - mean, d3 = p.w - mean;
      float var = wsum(d0 * d0 + d1 * d1 + d2 * d2 + d3 * d3) * (1.f / 256.f);
      float rstd = rsqrtf(var + 1e-6f);
      h4 z;
      z[0] = (_Float16)(d0 * rstd * gz.x + bz.x);
      z[1] = (_Float16)(d1 * rstd * gz.y + bz.y);
      z[2] = (_Float16)(d2 * rstd * gz.z + bz.z);
      z[3] = (_Float16)(d3 * rstd * gz.w + bz.w);
      *(h4*)(smem + ((n * 512 + lane * 8) ^ ((n & 7) << 4))) = z;
    }
  }
  __syncthreads();

  f32x4 zz = {0.f, 0.f, 0.f, 0.f};
  f32x4 oacc[4][2];   // out col = w*32 + nt*16 + lr, tok = t*16 + lk*4 + r
  #pragma unroll
  for (int t = 0; t < 4; ++t) { oacc[t][0] = zz; oacc[t][1] = zz; }

  for (int ch = 0; ch < 4; ++ch) {
    // ---- fc1 chunk: F = ZN @ W1[:, ch*256 + w*32 .. +32) ----
    f32x4 facc[4][2];
    #pragma unroll
    for (int t = 0; t < 4; ++t) { facc[t][0] = zz; facc[t][1] = zz; }
    {
      const _Float16* w1p = w1h + (size_t)(ch * 256 + w * 32 + lr) * 256 + lk * 8;
      #pragma unroll
      for (int ks = 0; ks < 8; ++ks) {
        const int ko = ks * 64 + lk * 16;
        h8 b0 = *(const h8*)(w1p + ks * 32);
        h8 b1 = *(const h8*)(w1p + 16 * 256 + ks * 32);
        #pragma unroll
        for (int t = 0; t < 4; ++t) {
          h8 a = *(const h8*)(smem + (((t * 16 + lr) * 512 + ko) ^ swz));
          facc[t][0] = MFMA16(a, b0, facc[t][0]);
          facc[t][1] = MFMA16(a, b1, facc[t][1]);
        }
      }
    }
    // ---- GELU -> H fp16 (col = w*32 + nt*16 + lr -> byte w*64 + nt*32 + lr*2) ----
    #pragma unroll
    for (int nt = 0; nt < 2; ++nt) {
      const float bb = fb1[ch * 256 + w * 32 + nt * 16 + lr];
      #pragma unroll
      for (int t = 0; t < 4; ++t) {
        #pragma unroll
        for (int r = 0; r < 4; ++r) {
          float a = facc[t][nt][r] + bb;
          float gl = 0.5f * a * (1.f + erff(a * 0.70710678118654752f));
          const int tok = t * 16 + lk * 4 + r;
          *(_Float16*)(smem + MH_OFF +
                       ((tok * 512 + w * 64 + nt * 32 + lr * 2) ^ ((tok & 7) << 4))) =
              (_Float16)gl;
        }
      }
    }
    __syncthreads();
    // ---- fc2 accumulate: oacc += H @ W2[ch*256.., w*32 + nt*16 + lr] ----
    {
      const _Float16* w2p = w2h + (size_t)(w * 32 + lr) * 1024 + ch * 256 + lk * 8;
      #pragma unroll
      for (int ks = 0; ks < 8; ++ks) {
        const int ko = ks * 64 + lk * 16;
        h8 b0 = *(const h8*)(w2p + ks * 32);
        h8 b1 = *(const h8*)(w2p + 16 * 1024 + ks * 32);
        #pragma unroll
        for (int t = 0; t < 4; ++t) {
          h8 a = *(const h8*)(smem + MH_OFF + (((t * 16 + lr) * 512 + ko) ^ swz));
          oacc[t][0] = MFMA16(a, b0, oacc[t][0]);
          oacc[t][1] = MFMA16(a, b1, oacc[t][1]);
        }
      }
    }
    __syncthreads();   // protect H before next chunk's GELU writes; last iter: ZN/H now dead
  }

  // ---- stage mlp output f32 into full smem [64 tok][1024 B] (ZN+H regions, both dead) ----
  #pragma unroll
  for (int nt = 0; nt < 2; ++nt) {
    #pragma unroll
    for (int t = 0; t < 4; ++t) {
      #pragma unroll
      for (int r = 0; r < 4; ++r) {
        const int tok = t * 16 + lk * 4 + r;
        *(float*)(smem + tok * 1024 + (w * 32 + nt * 16 + lr) * 4) = oacc[t][nt][r];
      }
    }
  }
  __syncthreads();

  // ---- coalesced residual epilogue: io += mlp + fb2, float4 per lane ----
  {
    const float4 bv = ((const float4*)fb2)[lane];
    for (int n = w; n < 64; n += 8) {
      const float4 m = *(const float4*)(smem + n * 1024 + lane * 16);
      float* pio = io + (t0 + n) * 256 + lane * 4;
      float4 p = *(const float4*)pio;
      p.x += m.x + bv.x;
      p.y += m.y + bv.y;
      p.z += m.z + bv.z;
      p.w += m.w + bv.w;
      *(float4*)pio = p;
    }
  }
}

extern "C" void kernel_launch(void* const* d_in, const int* in_sizes, int n_in,
                              void* d_out, int out_size, void* d_ws, size_t ws_size,
                              hipStream_t stream) {
  const float* x     = (const float*)d_in[0];
  const float* amask = (const float*)d_in[1];
  const float* g1    = (const float*)d_in[2];
  const float* b1    = (const float*)d_in[3];
  const float* qkvw  = (const float*)d_in[4];
  const float* qkvb  = (const float*)d_in[5];
  const float* temp  = (const float*)d_in[6];
  const float* rtab  = (const float*)d_in[7];
  const float* pw    = (const float*)d_in[8];
  const float* pb    = (const float*)d_in[9];
  const float* g2    = (const float*)d_in[10];
  const float* b2    = (const float*)d_in[11];
  const float* w1    = (const float*)d_in[12];
  const float* fb1   = (const float*)d_in[13];
  const float* w2    = (const float*)d_in[14];
  const float* fb2   = (const float*)d_in[15];
  const int* rpi     = (const int*)d_in[16];
  // d_in[17], d_in[18] = H, W (fixed 56)

  char* ws = (char*)d_ws;
  _Float16* wsq = (_Float16*)ws;               // 393,216 B (768x256 fp16)
  _Float16* pwh = (_Float16*)(ws + 393216);    // 131,072 B (256x256 fp16)
  _Float16* w1h = (_Float16*)(ws + 524288);    //  524,288 B (1024x256 fp16)
  _Float16* w2h = (_Float16*)(ws + 1048576);   //  524,288 B (256x1024 fp16)
  float* btab   = (float*)(ws + 1572864);      //   76,832 B (8x2401 f32)
  float* io = (float*)d_out;

  k_prep_qkv<<<768, 256, 0, stream>>>(qkvw, wsq);
  k_prep_pw<<<256, 256, 0, stream>>>(pw, pwh);
  k_prep_w1<<<1024, 256, 0, stream>>>(w1, w1h);
  k_prep_w2<<<1024, 256, 0, stream>>>(w2, w2h);
  k_prep_btab<<<10, 256, 0, stream>>>(rpi, rtab, btab);
  k_attn<<<2048, 512, 0, stream>>>(x, wsq, pwh, qkvb, g1, b1, temp, btab,
                                   amask, pb, io);
  k_mlp2<<<1568, 512, 0, stream>>>(io, g2, b2, w1h, fb1, w2h, fb2);
}